// Round 16
// baseline (39.097 us; speedup 1.0000x reference)
//
#include <hip/hip_runtime.h>
#include <math.h>

#define Bn 8
#define Tn 128
#define Un 64
#define U1n 65
#define Vn 512
#define NEG (-1e30f)
#define LOG2E 1.4426950408889634f
#define LN2 0.6931471805599453f
#define EPH 520    // EP row stride in bf16 halves (1040B): conflict-free tiling
#define ETW 516    // ET row stride (dwords); reads are wave-uniform broadcasts
#define SROWS 208  // diagonal rows per batch (prefetch reaches row 206)
#define SDSZ (SROWS * 64)
#define MAGIC 0x5EC0DE5Au

template <int CTRL>
__device__ __forceinline__ float dpp_mv(float x) {
  return __int_as_float(__builtin_amdgcn_update_dpp(
      __float_as_int(x), __float_as_int(x), CTRL, 0xF, 0xF, false));
}

__device__ __forceinline__ float red_sum64(float m) {
  m += dpp_mv<0xB1>(m);   // quad_perm xor1
  m += dpp_mv<0x4E>(m);   // quad_perm xor2
  m += dpp_mv<0x141>(m);  // row_half_mirror
  m += dpp_mv<0x140>(m);  // row_mirror
  m += __shfl_xor(m, 16);
  m += __shfl_xor(m, 32);
  return m;
}

// lane l <- lane l-1's x; lane 0 <- fill (DPP old operand). Pure VALU.
__device__ __forceinline__ float wave_shr1_fill(float x, float fill) {
  return __int_as_float(__builtin_amdgcn_update_dpp(
      __float_as_int(fill), __float_as_int(x), 0x138, 0xF, 0xF, false));
}

__device__ __forceinline__ float hw_exp2(float x) {
  return __builtin_amdgcn_exp2f(x);
}
__device__ __forceinline__ float hw_log2(float x) {
  return __builtin_amdgcn_logf(x);
}

// logaddexp in log2 domain
__device__ __forceinline__ float laddexp2(float a, float b) {
  float mx = fmaxf(a, b), mn = fminf(a, b);
  return mx + hw_log2(1.f + hw_exp2(mn - mx));
}

// f32 -> bf16 round-to-nearest-even (inputs positive finite)
__device__ __forceinline__ unsigned short f2bf(float x) {
  unsigned u = __float_as_uint(x);
  u += 0x7fffu + ((u >> 16) & 1u);
  return (unsigned short)(u >> 16);
}

// LDS union: dots-phase buffers (~76KB) are dead once the epilogue stores
// complete; the alpha phase overlays its staged inputs (~105KB) on them.
union SMEM {
  struct {
    unsigned short EPh[U1n * EPH];  // e^pred rows, bf16
    float ETs[4 * ETW];             // e^trans row per wave, f32
    float pr0s[U1n];
    float prls[Un];
    int lbls[Un];
  } d;
  struct {
    float lb[SDSZ];   // diag LB, copied from global
    float ll[SDSZ];   // diag LL
    float l0[256];    // u=0 prefix column
  } a;
};

// Fused v3: phase 1 = R14 bf16-EP dots + R10 diagonal epilogue (all 256
// blocks); dflag release/acquire handoff (R11/R15 protocol). Phase 2 fix vs
// R15 (which spent ~30us on per-step dirty-remote-L2 reads): chunk-0 block's
// 4 waves each acquire-spin, then cooperatively bulk-copy the batch's
// lb/ll/l0 (107KB) into LDS ONCE (float4-coalesced; remote latency amortized
// over one transfer), then wave 0 runs the verified alpha body from LDS.
// Replay-safe (stale MAGIC -> reads previous replay's bit-identical data);
// first-call 0xAA garbage = finite denormal, confined to dead lanes.
__global__ __launch_bounds__(256) void rnnt_fused(
    const float* __restrict__ trans, const float* __restrict__ pred,
    const int* __restrict__ labels, const int* __restrict__ act_lens,
    const int* __restrict__ label_lens, float* __restrict__ lbD,
    float* __restrict__ llD, float* __restrict__ l0D,
    unsigned* __restrict__ dflag, float* __restrict__ out) {
  __shared__ SMEM sm;

  int b = blockIdx.x >> 5;
  int chunk = blockIdx.x & 31;
  int tid = threadIdx.x;
  int w = tid >> 6;
  int lane = tid & 63;
  int t = chunk * 4 + w;

  if (blockIdx.x == 0 && tid == 0)
    __hip_atomic_store(out, 0.f, __ATOMIC_RELEASE, __HIP_MEMORY_SCOPE_AGENT);

  // ---- phase 1: dots (R14 math, byte-identical) ----
  if (tid < U1n) {
    sm.d.pr0s[tid] = pred[((size_t)b * U1n + tid) * Vn];
    if (tid < Un) {
      int lbl = labels[b * Un + tid];
      sm.d.lbls[tid] = lbl;
      sm.d.prls[tid] = pred[((size_t)b * U1n + tid) * Vn + lbl];
    }
  }

  const float4* pred4 = (const float4*)(pred + (size_t)b * U1n * Vn);
#pragma unroll
  for (int k = 0; k < 33; ++k) {
    int idx = tid + k * 256;
    if (idx < U1n * 128) {
      int u = idx >> 7, j = idx & 127;
      float4 pv = pred4[u * 128 + j];
      ushort4 ev;
      ev.x = f2bf(hw_exp2(pv.x * LOG2E));
      ev.y = f2bf(hw_exp2(pv.y * LOG2E));
      ev.z = f2bf(hw_exp2(pv.z * LOG2E));
      ev.w = f2bf(hw_exp2(pv.w * LOG2E));
      *(ushort4*)&sm.d.EPh[u * EPH + j * 4] = ev;
    }
  }

  const float* trow = trans + ((size_t)b * Tn + t) * Vn;
  const float4* trow4 = (const float4*)trow;
  {
    float4 x0 = trow4[lane], x1 = trow4[lane + 64];
    float4 e0, e1;
    e0.x = hw_exp2(x0.x * LOG2E); e0.y = hw_exp2(x0.y * LOG2E);
    e0.z = hw_exp2(x0.z * LOG2E); e0.w = hw_exp2(x0.w * LOG2E);
    e1.x = hw_exp2(x1.x * LOG2E); e1.y = hw_exp2(x1.y * LOG2E);
    e1.z = hw_exp2(x1.z * LOG2E); e1.w = hw_exp2(x1.w * LOG2E);
    *(float4*)&sm.d.ETs[w * ETW + lane * 8] = e0;
    *(float4*)&sm.d.ETs[w * ETW + lane * 8 + 4] = e1;
  }
  __syncthreads();

  int u = lane;
  float ac0 = 0.f, ac1 = 0.f, ac2 = 0.f, ac3 = 0.f;
  int epb = u * EPH, etb = w * ETW;
#pragma unroll 4
  for (int vc = 0; vc < Vn; vc += 8) {
    uint4 ph = *(const uint4*)&sm.d.EPh[epb + vc];
    float4 etA = *(const float4*)&sm.d.ETs[etb + vc];
    float4 etB = *(const float4*)&sm.d.ETs[etb + vc + 4];
    ac0 = fmaf(etA.x, __uint_as_float(ph.x << 16), ac0);
    ac1 = fmaf(etA.y, __uint_as_float(ph.x & 0xffff0000u), ac1);
    ac2 = fmaf(etA.z, __uint_as_float(ph.y << 16), ac2);
    ac3 = fmaf(etA.w, __uint_as_float(ph.y & 0xffff0000u), ac3);
    ac0 = fmaf(etB.x, __uint_as_float(ph.z << 16), ac0);
    ac1 = fmaf(etB.y, __uint_as_float(ph.z & 0xffff0000u), ac1);
    ac2 = fmaf(etB.z, __uint_as_float(ph.w << 16), ac2);
    ac3 = fmaf(etB.w, __uint_as_float(ph.w & 0xffff0000u), ac3);
  }
  float dot = (ac0 + ac2) + (ac1 + ac3);

  float p64;
  {
    uint4 ph = *(const uint4*)&sm.d.EPh[64 * EPH + lane * 8];
    float4 tA = *(const float4*)&sm.d.ETs[etb + lane * 8];
    float4 tB = *(const float4*)&sm.d.ETs[etb + lane * 8 + 4];
    float part = tA.x * __uint_as_float(ph.x << 16) +
                 tA.y * __uint_as_float(ph.x & 0xffff0000u) +
                 tA.z * __uint_as_float(ph.y << 16) +
                 tA.w * __uint_as_float(ph.y & 0xffff0000u) +
                 tB.x * __uint_as_float(ph.z << 16) +
                 tB.y * __uint_as_float(ph.z & 0xffff0000u) +
                 tB.z * __uint_as_float(ph.w << 16) +
                 tB.w * __uint_as_float(ph.w & 0xffff0000u);
    p64 = red_sum64(part);
  }

  float tr0v = trow[0];
  float lse2 = hw_log2(dot);
  float lbv = (tr0v + sm.d.pr0s[u]) * LOG2E - lse2;
  float llv = (trow[sm.d.lbls[u]] + sm.d.prls[u]) * LOG2E - lse2;

  // diagonal stores (R10 epilogue): cell (t,u) -> row t+u
  float* lbDb = lbD + (size_t)b * SDSZ;
  float* llDb = llD + (size_t)b * SDSZ;
  if (lane == 0) {
    l0D[b * 256 + t] = lbv;  // u=0 blank column
    lbDb[(t + 64) * 64 + 63] = (tr0v + sm.d.pr0s[64]) * LOG2E - hw_log2(p64);
  } else {
    lbDb[(t + lane) * 64 + (lane - 1)] = lbv;
  }
  llDb[(t + lane) * 64 + lane] = llv;
  if (t == 0) lbDb[lane * 64 + lane] = NEG;  // t'=-1 diagonal patch

  __syncthreads();  // all waves' stores drained (vmcnt(0) before barrier)

  if (chunk != 0) {
    if (tid == 0)
      __hip_atomic_store(&dflag[b * 32 + chunk], MAGIC, __ATOMIC_RELEASE,
                         __HIP_MEMORY_SCOPE_AGENT);
    return;
  }

  // ---- handoff: every wave acquire-spins (each wave's later copy reads
  // are then ordered after its own acquire) ----
  {
    int idx = b * 32 + ((lane < 31) ? lane + 1 : 31);
    while (true) {
      unsigned v = __hip_atomic_load(&dflag[idx], __ATOMIC_ACQUIRE,
                                     __HIP_MEMORY_SCOPE_AGENT);
      if (!__any(v != MAGIC)) break;
      __builtin_amdgcn_s_sleep(1);
    }
  }

  // ---- bulk copy global -> LDS (one coalesced transfer; overlays sm.d) ----
  {
    const float4* slb = (const float4*)(lbD + (size_t)b * SDSZ);
    const float4* sll = (const float4*)(llD + (size_t)b * SDSZ);
    float4* dlb = (float4*)sm.a.lb;
    float4* dll = (float4*)sm.a.ll;
    for (int i = tid; i < SDSZ / 4; i += 256) {
      dlb[i] = slb[i];
      dll[i] = sll[i];
    }
    if (tid < 64) ((float4*)sm.a.l0)[tid] = ((const float4*)(l0D + b * 256))[tid];
  }
  __syncthreads();
  if (tid >= 64) return;
  int l = lane;

  // ---- phase 2: alpha (R10 body, reads from LDS) ----
  int ti = act_lens[b] - 1;  // [63,127]
  int ui = label_lens[b];    // [32,64]
  int s_end = ti + ui;       // rec produced at s = s_end-1
  bool is_rec = (l == ui - 1);

  float a = NEG, p = 0.f, rec = 0.f;
  float lbB[16], llB[16], l0B[16];
#pragma unroll
  for (int k = 0; k < 16; ++k) {
    lbB[k] = sm.a.lb[k * 64 + l];
    llB[k] = sm.a.ll[k * 64 + l];
    l0B[k] = sm.a.l0[k];
  }

  for (int sb = 0; sb < s_end; sb += 16) {
#pragma unroll
    for (int k = 0; k < 16; ++k) {
      int s = sb + k;
      float lb_t = lbB[k], ll_t = llB[k], l0_t = l0B[k];
      lbB[k] = sm.a.lb[(s + 16) * 64 + l];
      llB[k] = sm.a.ll[(s + 16) * 64 + l];
      l0B[k] = sm.a.l0[s + 16];

      float nb = wave_shr1_fill(a, p);  // lane0 <- p (alpha[t][0])
      float vert = a + lb_t;            // alpha[t-1][u] + LB[t-1][u]
      float horiz = nb + ll_t;          // alpha[t][u-1] + LL[t][u-1]
      float an = laddexp2(vert, horiz);
      int tt = s - l;
      a = (tt >= 0) ? an : NEG;
      p += l0_t;
      if ((tt == ti) & is_rec) rec = an;
    }
  }

  float r = __shfl(rec, ui - 1);
  if (l == 0) {
    float lbf = sm.a.lb[s_end * 64 + (ui - 1)];  // LB[ti][ui] (scaled)
    atomicAdd(out, -(r + lbf) * LN2);
  }
}

extern "C" void kernel_launch(void* const* d_in, const int* in_sizes, int n_in,
                              void* d_out, int out_size, void* d_ws, size_t ws_size,
                              hipStream_t stream) {
  const float* trans = (const float*)d_in[0];
  const float* pred = (const float*)d_in[1];
  const int* labels = (const int*)d_in[2];
  const int* act_lens = (const int*)d_in[3];
  const int* label_lens = (const int*)d_in[4];
  float* out = (float*)d_out;

  float* lbD = (float*)d_ws;             // 8 * SDSZ
  float* llD = lbD + Bn * SDSZ;          // 8 * SDSZ
  float* l0D = llD + Bn * SDSZ;          // 8 * 256
  unsigned* dflag = (unsigned*)(l0D + Bn * 256);  // 256

  rnnt_fused<<<Bn * 32, 256, 0, stream>>>(trans, pred, labels, act_lens,
                                          label_lens, lbD, llD, l0D, dflag,
                                          out);
}

// Round 17
// 26.103 us; speedup vs baseline: 1.4978x; 1.4978x over previous
//
#include <hip/hip_runtime.h>
#include <math.h>

#define Bn 8
#define Tn 128
#define Un 64
#define U1n 65
#define Vn 512
#define NEG (-1e30f)
#define LOG2E 1.4426950408889634f
#define LN2 0.6931471805599453f
#define VP 516  // LDS row stride (dwords): lane-delta 4 banks -> conflict-free

template <int CTRL>
__device__ __forceinline__ float dpp_mv(float x) {
  return __int_as_float(__builtin_amdgcn_update_dpp(
      __float_as_int(x), __float_as_int(x), CTRL, 0xF, 0xF, false));
}

__device__ __forceinline__ float red_sum64(float m) {
  m += dpp_mv<0xB1>(m);   // quad_perm xor1
  m += dpp_mv<0x4E>(m);   // quad_perm xor2
  m += dpp_mv<0x141>(m);  // row_half_mirror
  m += dpp_mv<0x140>(m);  // row_mirror
  m += __shfl_xor(m, 16);
  m += __shfl_xor(m, 32);
  return m;
}

// lane l <- lane l-1's x; lane 0 <- fill (DPP old operand). Pure VALU.
__device__ __forceinline__ float wave_shr1_fill(float x, float fill) {
  return __int_as_float(__builtin_amdgcn_update_dpp(
      __float_as_int(fill), __float_as_int(x), 0x138, 0xF, 0xF, false));
}

__device__ __forceinline__ float hw_exp2(float x) {
  return __builtin_amdgcn_exp2f(x);
}
__device__ __forceinline__ float hw_log2(float x) {
  return __builtin_amdgcn_logf(x);
}

// logaddexp in log2 domain
__device__ __forceinline__ float laddexp2(float a, float b) {
  float mx = fmaxf(a, b), mn = fminf(a, b);
  return mx + hw_log2(1.f + hw_exp2(mn - mx));
}

// Kernel 1 (rnnt_dots): lse via dot products of pre-exponentiated rows:
// sum_v e^{tr_v+pr_v} = sum_v e^{tr_v} * e^{pr_v}. One block per (b, 4 t's):
// stage E_pr for all 65 u in LDS (stride 516 dwords: lane-delta = 4 banks,
// conflict-free minimum for b128); each wave owns one t, lane u accumulates
// dot[u] over V. Outputs TRANSPOSED [b][u][t], pre-scaled by log2(e), so the
// alpha kernel's per-lane streams are row-contiguous (L1-resident).
__global__ __launch_bounds__(256) void rnnt_dots(
    const float* __restrict__ trans, const float* __restrict__ pred,
    const int* __restrict__ labels, float* __restrict__ lbT,
    float* __restrict__ llT, float* __restrict__ out) {
  __shared__ float EPs[U1n * VP];   // e^pred rows, [u][VP]
  __shared__ float ETs[4 * VP];     // e^trans row per wave
  __shared__ float pr0s[U1n];       // pred[b][u][0]
  __shared__ float prls[Un];        // pred[b][u][labels[b][u]]
  __shared__ int lbls[Un];

  if (blockIdx.x == 0 && threadIdx.x == 0) out[0] = 0.f;

  int b = blockIdx.x >> 5;
  int chunk = blockIdx.x & 31;
  int tid = threadIdx.x;
  int w = tid >> 6;
  int lane = tid & 63;
  int t = chunk * 4 + w;

  if (tid < U1n) {
    pr0s[tid] = pred[((size_t)b * U1n + tid) * Vn];
    if (tid < Un) {
      int lbl = labels[b * Un + tid];
      lbls[tid] = lbl;
      prls[tid] = pred[((size_t)b * U1n + tid) * Vn + lbl];
    }
  }

  const float4* pred4 = (const float4*)(pred + (size_t)b * U1n * Vn);
#pragma unroll
  for (int k = 0; k < 33; ++k) {
    int idx = tid + k * 256;
    if (idx < U1n * 128) {
      int u = idx >> 7, j = idx & 127;
      float4 pv = pred4[u * 128 + j];
      float4 ev;
      ev.x = hw_exp2(pv.x * LOG2E);
      ev.y = hw_exp2(pv.y * LOG2E);
      ev.z = hw_exp2(pv.z * LOG2E);
      ev.w = hw_exp2(pv.w * LOG2E);
      *(float4*)&EPs[u * VP + j * 4] = ev;
    }
  }

  const float* trow = trans + ((size_t)b * Tn + t) * Vn;
  const float4* trow4 = (const float4*)trow;
  {
    float4 x0 = trow4[lane], x1 = trow4[lane + 64];
    float4 e0, e1;
    e0.x = hw_exp2(x0.x * LOG2E); e0.y = hw_exp2(x0.y * LOG2E);
    e0.z = hw_exp2(x0.z * LOG2E); e0.w = hw_exp2(x0.w * LOG2E);
    e1.x = hw_exp2(x1.x * LOG2E); e1.y = hw_exp2(x1.y * LOG2E);
    e1.z = hw_exp2(x1.z * LOG2E); e1.w = hw_exp2(x1.w * LOG2E);
    *(float4*)&ETs[w * VP + lane * 8] = e0;
    *(float4*)&ETs[w * VP + lane * 8 + 4] = e1;
  }
  __syncthreads();

  int u = lane;
  float ac0 = 0.f, ac1 = 0.f, ac2 = 0.f, ac3 = 0.f;
  int epb = u * VP, etb = w * VP;
#pragma unroll 4
  for (int vc = 0; vc < Vn; vc += 4) {
    float4 ep = *(const float4*)&EPs[epb + vc];
    float4 et = *(const float4*)&ETs[etb + vc];
    ac0 += et.x * ep.x;
    ac1 += et.y * ep.y;
    ac2 += et.z * ep.z;
    ac3 += et.w * ep.w;
  }
  float dot = (ac0 + ac2) + (ac1 + ac3);

  // u = 64 tail: lane-distributed dot + wave reduce
  float p64;
  {
    float4 eA = *(const float4*)&EPs[64 * VP + lane * 8];
    float4 eB = *(const float4*)&EPs[64 * VP + lane * 8 + 4];
    float4 tA = *(const float4*)&ETs[etb + lane * 8];
    float4 tB = *(const float4*)&ETs[etb + lane * 8 + 4];
    float part = eA.x * tA.x + eA.y * tA.y + eA.z * tA.z + eA.w * tA.w +
                 eB.x * tB.x + eB.y * tB.y + eB.z * tB.z + eB.w * tB.w;
    p64 = red_sum64(part);
  }

  float tr0v = trow[0];
  float lse2 = hw_log2(dot);
  // transposed, pre-scaled by log2e
  lbT[((size_t)b * U1n + u) * Tn + t] = (tr0v + pr0s[u]) * LOG2E - lse2;
  float trl = trow[lbls[u]];  // per-lane gather within the row
  llT[((size_t)b * Un + u) * Tn + t] = (trl + prls[u]) * LOG2E - lse2;
  if (lane == 0) {
    lbT[((size_t)b * U1n + 64) * Tn + t] =
        (tr0v + pr0s[64]) * LOG2E - hw_log2(p64);
  }
}

// Kernel 2: one wave per batch, u-in-lanes register wavefront. Lane l owns
// column u=l+1; u=0 is a running cumsum p (DPP old-operand feeds it to lane 0
// with no cndmask on the chain). One laddexp2 per step; early exit at
// s_end = ti+ui (rec consumed at s = ti+ui-1). lp streamed from global
// (L1-resident per-lane rows), prefetched 8 deep in a register ring.
__global__ __launch_bounds__(64) void rnnt_alpha(
    const float* __restrict__ lbT, const float* __restrict__ llT,
    const int* __restrict__ act_lens, const int* __restrict__ label_lens,
    float* __restrict__ out) {
  int b = blockIdx.x;
  int l = threadIdx.x;

  const float* LBrow = lbT + ((size_t)b * U1n + l + 1) * Tn;  // LB[.][u=l+1]
  const float* LLrow = llT + ((size_t)b * Un + l) * Tn;       // LL[.][u-1=l]
  const float* L0row = lbT + (size_t)b * U1n * Tn;            // LB[.][u=0]

  int ti = act_lens[b] - 1;  // [63,127]
  int ui = label_lens[b];    // [32,64]
  int s_end = ti + ui;       // rec produced at s = s_end-1
  bool is_rec = (l == ui - 1);

  float a = NEG, p = 0.f, rec = 0.f;
  float lbB[8], llB[8], l0B[8];
#pragma unroll
  for (int k = 0; k < 8; ++k) {
    lbB[k] = LBrow[k - l - 1];
    llB[k] = LLrow[k - l];
    l0B[k] = L0row[k];
  }

  for (int sb = 0; sb < s_end; sb += 8) {
#pragma unroll
    for (int k = 0; k < 8; ++k) {
      int s = sb + k;
      float lb_t = lbB[k], ll_t = llB[k], l0_t = l0B[k];
      lbB[k] = LBrow[s + 8 - l - 1];
      llB[k] = LLrow[s + 8 - l];
      l0B[k] = L0row[s + 8];

      float nb = wave_shr1_fill(a, p);  // lane0 <- p (alpha[t][0]), no cndmask
      float vert = a + lb_t;            // alpha[t-1][u] + LB[t-1][u]
      float horiz = nb + ll_t;          // alpha[t][u-1] + LL[t][u-1]
      float an = laddexp2(vert, horiz);
      int t = s - l;
      a = (t >= 0) ? an : NEG;
      p += l0_t;
      if ((t == ti) & is_rec) rec = an;
    }
  }

  float r = __shfl(rec, ui - 1);
  if (l == 0) {
    float lbv = lbT[((size_t)b * U1n + ui) * Tn + ti];  // scaled blank lp
    atomicAdd(out, -(r + lbv) * LN2);
  }
}

extern "C" void kernel_launch(void* const* d_in, const int* in_sizes, int n_in,
                              void* d_out, int out_size, void* d_ws, size_t ws_size,
                              hipStream_t stream) {
  const float* trans = (const float*)d_in[0];
  const float* pred = (const float*)d_in[1];
  const int* labels = (const int*)d_in[2];
  const int* act_lens = (const int*)d_in[3];
  const int* label_lens = (const int*)d_in[4];
  float* out = (float*)d_out;

  // [64-float guard][lbT 66560][llT 65536][slack] — guard absorbs the ring's
  // negative prologue indices; trailing reads stay in-allocation.
  float* lbT = (float*)d_ws + 64;
  float* llT = lbT + Bn * U1n * Tn;

  rnnt_dots<<<Bn * 32, 256, 0, stream>>>(trans, pred, labels, lbT, llT, out);
  rnnt_alpha<<<Bn, 64, 0, stream>>>(lbT, llT, act_lens, label_lens, out);
}